// Round 1
// baseline (1048.559 us; speedup 1.0000x reference)
//
#include <hip/hip_runtime.h>
#include <math.h>

#define N_NODES 231
#define N_EDGES 1848
#define TOT_E   (N_EDGES + N_NODES)   // 2079 incl. self loops
#define GPB     8                     // graphs per block
#define NT      256

// ---------------- setup: build dst-CSR + norms into ws -------------------
// ws layout (4-byte elements):
//   [0,   256)   offs  (int, 232 used)
//   [256, 2368)  esrc  (int, 2079 used)
//   [2368,4480)  enorm (float, 2079 used)
__global__ void gcn_setup(const int* __restrict__ ei,   // [2, E] int32
                          int* __restrict__ offs,
                          int* __restrict__ esrc,
                          float* __restrict__ enorm) {
    __shared__ int   deg[N_NODES];
    __shared__ float invs[N_NODES];
    __shared__ int   soffs[N_NODES + 1];
    __shared__ int   fill[N_NODES];
    const int tid = threadIdx.x;

    for (int i = tid; i < N_NODES; i += NT) { deg[i] = 1; fill[i] = 0; } // +1 self loop
    __syncthreads();
    for (int e = tid; e < N_EDGES; e += NT)
        atomicAdd(&deg[ei[N_EDGES + e]], 1);       // in-degree on dst
    __syncthreads();
    if (tid == 0) {
        int acc = 0;
        for (int i = 0; i < N_NODES; ++i) { soffs[i] = acc; acc += deg[i]; }
        soffs[N_NODES] = acc;  // == TOT_E
    }
    __syncthreads();
    for (int i = tid; i < N_NODES; i += NT)
        invs[i] = rsqrtf((float)deg[i]);           // deg >= 1 always
    __syncthreads();
    for (int e = tid; e < N_EDGES; e += NT) {
        int s = ei[e], d = ei[N_EDGES + e];
        int p = soffs[d] + atomicAdd(&fill[d], 1);
        esrc[p]  = s;
        enorm[p] = invs[s] * invs[d];
    }
    for (int i = tid; i < N_NODES; i += NT) {      // self loops
        int p = soffs[i] + atomicAdd(&fill[i], 1);
        esrc[p]  = i;
        enorm[p] = invs[i] * invs[i];
    }
    __syncthreads();
    for (int i = tid; i <= N_NODES; i += NT) offs[i] = soffs[i];
}

// ---------------- fused GCN x3 + MLP, GPB graphs per block ----------------
__global__ __launch_bounds__(NT)
void gcn_lenet(const float* __restrict__ x,        // [B,231,12]
               const int* __restrict__ offs,
               const int* __restrict__ esrc,
               const float* __restrict__ enorm,
               const float* __restrict__ W1, const float* __restrict__ b1,
               const float* __restrict__ W2, const float* __restrict__ b2,
               const float* __restrict__ W3, const float* __restrict__ b3,
               const float* __restrict__ Wf1, const float* __restrict__ bf1,
               const float* __restrict__ Wf2, const float* __restrict__ bf2,
               const float* __restrict__ Wf3, const float* __restrict__ bf3,
               float* __restrict__ out, int B) {
    __shared__ float sX[2772];          // x tile; later reused for t2/h2/t3
    __shared__ float sT1[1848];
    __shared__ float sH1[1848];
    __shared__ float sH3[GPB * 462];
    __shared__ float sZ1[GPB * 120];
    __shared__ float sZ2[GPB * 84];
    __shared__ float sW1[96], sB1v[8], sW2[32], sB2v[4], sW3[8], sB3v[2];
    __shared__ float sBf1[120], sBf2[84], sBf3[10];
    float* sT2 = sX;                    // 924 floats
    float* sH2 = sX + 1024;             // 924 floats
    float* sT3 = sX + 2048;             // 462 floats (2048+462 <= 2772)

    const int tid = threadIdx.x;
    if (tid < 96)  sW1[tid]  = W1[tid];
    if (tid < 8)   sB1v[tid] = b1[tid];
    if (tid < 32)  sW2[tid]  = W2[tid];
    if (tid < 4)   sB2v[tid] = b2[tid];
    if (tid < 8)   sW3[tid]  = W3[tid];
    if (tid < 2)   sB3v[tid] = b3[tid];
    if (tid < 120) sBf1[tid] = bf1[tid];
    if (tid < 84)  sBf2[tid] = bf2[tid];
    if (tid < 10)  sBf3[tid] = bf3[tid];

    for (int g = 0; g < GPB; ++g) {
        const int gid = blockIdx.x * GPB + g;
        __syncthreads();                // protect sX reuse from prev iter
        if (gid >= B) break;            // block-uniform

        // ---- load x tile (2772 floats = 693 float4, 16B-aligned) ----
        const float4* xs = (const float4*)(x + (size_t)gid * 2772);
        float4* xd = (float4*)sX;
        for (int i = tid; i < 693; i += NT) xd[i] = xs[i];
        __syncthreads();

        // ---- t1 = x @ W1   [231,8] ----
        for (int o = tid; o < 1848; o += NT) {
            int n = o >> 3, k = o & 7;
            const float* xr = sX + n * 12;
            float acc = 0.f;
#pragma unroll
            for (int f = 0; f < 12; ++f) acc += xr[f] * sW1[f * 8 + k];
            sT1[o] = acc;
        }
        __syncthreads();

        // ---- h1 = tanh(agg(t1) + b1) ----
        for (int o = tid; o < 1848; o += NT) {
            int n = o >> 3, k = o & 7;
            float acc = sB1v[k];
            int e1 = offs[n + 1];
            for (int e = offs[n]; e < e1; ++e)
                acc += enorm[e] * sT1[esrc[e] * 8 + k];
            sH1[o] = tanhf(acc);
        }
        __syncthreads();

        // ---- t2 = h1 @ W2   [231,4] (into sX[0:924]) ----
        for (int o = tid; o < 924; o += NT) {
            int n = o >> 2, k = o & 3;
            const float* hr = sH1 + n * 8;
            float acc = 0.f;
#pragma unroll
            for (int f = 0; f < 8; ++f) acc += hr[f] * sW2[f * 4 + k];
            sT2[o] = acc;
        }
        __syncthreads();

        // ---- h2 = tanh(agg(t2) + b2) ----
        for (int o = tid; o < 924; o += NT) {
            int n = o >> 2, k = o & 3;
            float acc = sB2v[k];
            int e1 = offs[n + 1];
            for (int e = offs[n]; e < e1; ++e)
                acc += enorm[e] * sT2[esrc[e] * 4 + k];
            sH2[o] = tanhf(acc);
        }
        __syncthreads();

        // ---- t3 = h2 @ W3   [231,2] ----
        for (int o = tid; o < 462; o += NT) {
            int n = o >> 1, k = o & 1;
            const float* hr = sH2 + n * 4;
            float acc = 0.f;
#pragma unroll
            for (int f = 0; f < 4; ++f) acc += hr[f] * sW3[f * 2 + k];
            sT3[o] = acc;
        }
        __syncthreads();

        // ---- h3 = agg(t3) + b3  → sH3[g]  (flat layout n*2+k == o) ----
        for (int o = tid; o < 462; o += NT) {
            int n = o >> 1, k = o & 1;
            float acc = sB3v[k];
            int e1 = offs[n + 1];
            for (int e = offs[n]; e < e1; ++e)
                acc += enorm[e] * sT3[esrc[e] * 2 + k];
            sH3[g * 462 + o] = acc;
        }
    }
    __syncthreads();

    // ---- FC1: z1 = elu(h3 @ Wf1 + bf1)   [G,120] ----
    for (int o = tid; o < GPB * 120; o += NT) {
        int g = o / 120, j = o - g * 120;
        if (blockIdx.x * GPB + g >= B) break;
        const float* h = sH3 + g * 462;
        float acc = sBf1[j];
        for (int i = 0; i < 462; ++i) acc += h[i] * Wf1[i * 120 + j];
        sZ1[o] = acc > 0.f ? acc : expm1f(acc);
    }
    __syncthreads();

    // ---- FC2: z2 = elu(z1 @ Wf2 + bf2)   [G,84] ----
    for (int o = tid; o < GPB * 84; o += NT) {
        int g = o / 84, j = o - g * 84;
        if (blockIdx.x * GPB + g >= B) break;
        const float* zz = sZ1 + g * 120;
        float acc = sBf2[j];
        for (int i = 0; i < 120; ++i) acc += zz[i] * Wf2[i * 84 + j];
        sZ2[o] = acc > 0.f ? acc : expm1f(acc);
    }
    __syncthreads();

    // ---- FC3 + store   [G,10] ----
    for (int o = tid; o < GPB * 10; o += NT) {
        int g = o / 10, j = o - g * 10;
        const int gid = blockIdx.x * GPB + g;
        if (gid >= B) break;
        const float* zz = sZ2 + g * 84;
        float acc = sBf3[j];
        for (int i = 0; i < 84; ++i) acc += zz[i] * Wf3[i * 10 + j];
        out[(size_t)gid * 10 + j] = acc;
    }
}

extern "C" void kernel_launch(void* const* d_in, const int* in_sizes, int n_in,
                              void* d_out, int out_size, void* d_ws, size_t ws_size,
                              hipStream_t stream) {
    const float* x   = (const float*)d_in[0];
    const int*   ei  = (const int*)d_in[1];
    const float* W1  = (const float*)d_in[2];
    const float* b1  = (const float*)d_in[3];
    const float* W2  = (const float*)d_in[4];
    const float* b2  = (const float*)d_in[5];
    const float* W3  = (const float*)d_in[6];
    const float* b3  = (const float*)d_in[7];
    const float* Wf1 = (const float*)d_in[8];
    const float* bf1 = (const float*)d_in[9];
    const float* Wf2 = (const float*)d_in[10];
    const float* bf2 = (const float*)d_in[11];
    const float* Wf3 = (const float*)d_in[12];
    const float* bf3 = (const float*)d_in[13];
    float* out = (float*)d_out;

    const int B = in_sizes[0] / (N_NODES * 12);

    int*   offs  = (int*)d_ws;
    int*   esrc  = offs + 256;
    float* enorm = (float*)(esrc + 2112);

    gcn_setup<<<1, NT, 0, stream>>>(ei, offs, esrc, enorm);

    const int nblk = (B + GPB - 1) / GPB;
    gcn_lenet<<<nblk, NT, 0, stream>>>(x, offs, esrc, enorm,
                                       W1, b1, W2, b2, W3, b3,
                                       Wf1, bf1, Wf2, bf2, Wf3, bf3,
                                       out, B);
}

// Round 2
// 441.084 us; speedup vs baseline: 2.3772x; 2.3772x over previous
//
#include <hip/hip_runtime.h>
#include <math.h>

#define N_NODES 231
#define N_EDGES 1848
#define TOT_E   (N_EDGES + N_NODES)   // 2079 incl. self loops
#define NT      256
#define GT      32                    // graphs per FC block
#define HSTR    464                   // padded h3 row stride (floats), 16B-aligned rows

__device__ __forceinline__ float fast_tanh(float x) {
    // tanh(x) = 1 - 2/(exp(2x)+1); robust at +-inf, ~1e-6 abs err
    float e = __expf(2.f * x);
    return 1.f - 2.f * __builtin_amdgcn_rcpf(e + 1.f);
}

// ---------------- setup: build dst-CSR + norms into ws -------------------
__global__ void gcn_setup(const int* __restrict__ ei,   // [2, E] int32
                          int* __restrict__ offs,       // [232]
                          short* __restrict__ esrc,     // [2080]
                          float* __restrict__ enorm) {  // [2080]
    __shared__ int   deg[N_NODES];
    __shared__ float invs[N_NODES];
    __shared__ int   soffs[N_NODES + 1];
    __shared__ int   fill[N_NODES];
    const int tid = threadIdx.x;

    for (int i = tid; i < N_NODES; i += NT) { deg[i] = 1; fill[i] = 0; } // +1 self loop
    __syncthreads();
    for (int e = tid; e < N_EDGES; e += NT)
        atomicAdd(&deg[ei[N_EDGES + e]], 1);       // in-degree on dst
    __syncthreads();
    if (tid == 0) {
        int acc = 0;
        for (int i = 0; i < N_NODES; ++i) { soffs[i] = acc; acc += deg[i]; }
        soffs[N_NODES] = acc;  // == TOT_E
    }
    __syncthreads();
    for (int i = tid; i < N_NODES; i += NT)
        invs[i] = rsqrtf((float)deg[i]);
    __syncthreads();
    for (int e = tid; e < N_EDGES; e += NT) {
        int s = ei[e], d = ei[N_EDGES + e];
        int p = soffs[d] + atomicAdd(&fill[d], 1);
        esrc[p]  = (short)s;
        enorm[p] = invs[s] * invs[d];
    }
    for (int i = tid; i < N_NODES; i += NT) {      // self loops
        int p = soffs[i] + atomicAdd(&fill[i], 1);
        esrc[p]  = (short)i;
        enorm[p] = invs[i] * invs[i];
    }
    __syncthreads();
    for (int i = tid; i <= N_NODES; i += NT) offs[i] = soffs[i];
    // pad tail so vectorized staging reads defined data
    if (tid == 0) { esrc[TOT_E] = 0; enorm[TOT_E] = 0.f; }
}

// ---------------- kernel A: GCN x3, one graph per block -------------------
__global__ __launch_bounds__(NT)
void gcn_nodes(const float* __restrict__ x,        // [B,231,12]
               const int* __restrict__ goffs,
               const short* __restrict__ gsrc,
               const float* __restrict__ gnrm,
               const float* __restrict__ W1, const float* __restrict__ b1,
               const float* __restrict__ W2, const float* __restrict__ b2,
               const float* __restrict__ W3, const float* __restrict__ b3,
               float* __restrict__ hbuf, int B) {
    __shared__ int   sOff[232];
    __shared__ short sSrc[2080] __attribute__((aligned(16)));
    __shared__ float sNrm[2080] __attribute__((aligned(16)));
    __shared__ float sT1[1848]  __attribute__((aligned(16)));
    __shared__ float sT2[928]   __attribute__((aligned(16)));
    __shared__ float sW1[96], sB1[8], sW2[32], sB2[4], sW3[8], sB3[2];

    const int tid = threadIdx.x;
    const int g   = blockIdx.x;

    // ---- cooperative staging of CSR + weights ----
    for (int i = tid; i < 58;  i += NT) ((int4*)sOff)[i]   = ((const int4*)goffs)[i];
    for (int i = tid; i < 260; i += NT) ((int4*)sSrc)[i]   = ((const int4*)gsrc)[i];
    for (int i = tid; i < 520; i += NT) ((float4*)sNrm)[i] = ((const float4*)gnrm)[i];
    if (tid < 96)                 sW1[tid]       = W1[tid];
    else if (tid < 104)           sB1[tid - 96]  = b1[tid - 96];
    else if (tid < 136)           sW2[tid - 104] = W2[tid - 104];
    else if (tid < 140)           sB2[tid - 136] = b2[tid - 136];
    else if (tid < 148)           sW3[tid - 140] = W3[tid - 140];
    else if (tid < 150)           sB3[tid - 148] = b3[tid - 148];

    // ---- each thread loads its own x row into registers ----
    float xr[12];
    if (tid < N_NODES) {
        const float4* xp = (const float4*)(x + (size_t)g * 2772 + tid * 12);
        float4 a = xp[0], bb = xp[1], c = xp[2];
        xr[0]=a.x; xr[1]=a.y; xr[2]=a.z;  xr[3]=a.w;
        xr[4]=bb.x;xr[5]=bb.y;xr[6]=bb.z; xr[7]=bb.w;
        xr[8]=c.x; xr[9]=c.y; xr[10]=c.z; xr[11]=c.w;
    }
    __syncthreads();

    // ---- t1 = x @ W1  (per node, 8 feats in regs) ----
    if (tid < N_NODES) {
        float t[8];
#pragma unroll
        for (int k = 0; k < 8; ++k) t[k] = 0.f;
#pragma unroll
        for (int f = 0; f < 12; ++f) {
            float xv = xr[f];
#pragma unroll
            for (int k = 0; k < 8; ++k) t[k] = fmaf(xv, sW1[f*8 + k], t[k]);
        }
#pragma unroll
        for (int k = 0; k < 8; ++k) sT1[tid*8 + k] = t[k];
    }
    __syncthreads();

    // ---- h1 = tanh(agg(t1)+b1);  t2 = h1 @ W2 ----
    if (tid < N_NODES) {
        float a[8];
#pragma unroll
        for (int k = 0; k < 8; ++k) a[k] = 0.f;
        const int e0 = sOff[tid], e1 = sOff[tid + 1];
        for (int e = e0; e < e1; ++e) {
            float w = sNrm[e];
            int   s = sSrc[e];
            const float4* p = (const float4*)&sT1[s << 3];
            float4 u = p[0], v = p[1];
            a[0] = fmaf(w, u.x, a[0]); a[1] = fmaf(w, u.y, a[1]);
            a[2] = fmaf(w, u.z, a[2]); a[3] = fmaf(w, u.w, a[3]);
            a[4] = fmaf(w, v.x, a[4]); a[5] = fmaf(w, v.y, a[5]);
            a[6] = fmaf(w, v.z, a[6]); a[7] = fmaf(w, v.w, a[7]);
        }
        float h[8];
#pragma unroll
        for (int k = 0; k < 8; ++k) h[k] = fast_tanh(a[k] + sB1[k]);
        float t2v[4] = {0.f, 0.f, 0.f, 0.f};
#pragma unroll
        for (int f = 0; f < 8; ++f) {
            float hv = h[f];
#pragma unroll
            for (int c = 0; c < 4; ++c) t2v[c] = fmaf(hv, sW2[f*4 + c], t2v[c]);
        }
        *(float4*)&sT2[tid*4] = make_float4(t2v[0], t2v[1], t2v[2], t2v[3]);
    }
    __syncthreads();

    // ---- h2 = tanh(agg(t2)+b2);  t3 = h2 @ W3 (into sT1, reuse) ----
    if (tid < N_NODES) {
        float a[4] = {0.f, 0.f, 0.f, 0.f};
        const int e0 = sOff[tid], e1 = sOff[tid + 1];
        for (int e = e0; e < e1; ++e) {
            float w = sNrm[e];
            int   s = sSrc[e];
            float4 u = *(const float4*)&sT2[s << 2];
            a[0] = fmaf(w, u.x, a[0]); a[1] = fmaf(w, u.y, a[1]);
            a[2] = fmaf(w, u.z, a[2]); a[3] = fmaf(w, u.w, a[3]);
        }
        float h[4];
#pragma unroll
        for (int k = 0; k < 4; ++k) h[k] = fast_tanh(a[k] + sB2[k]);
        float t3v[2] = {0.f, 0.f};
#pragma unroll
        for (int f = 0; f < 4; ++f) {
            t3v[0] = fmaf(h[f], sW3[f*2 + 0], t3v[0]);
            t3v[1] = fmaf(h[f], sW3[f*2 + 1], t3v[1]);
        }
        *(float2*)&sT1[tid*2] = make_float2(t3v[0], t3v[1]);
    }
    __syncthreads();

    // ---- h3 = agg(t3)+b3  → hbuf[g][464] ----
    if (tid < N_NODES) {
        float a0 = 0.f, a1 = 0.f;
        const int e0 = sOff[tid], e1 = sOff[tid + 1];
        for (int e = e0; e < e1; ++e) {
            float w = sNrm[e];
            int   s = sSrc[e];
            float2 u = *(const float2*)&sT1[s << 1];
            a0 = fmaf(w, u.x, a0);
            a1 = fmaf(w, u.y, a1);
        }
        ((float2*)(hbuf + (size_t)g * HSTR))[tid] = make_float2(a0 + sB3[0], a1 + sB3[1]);
    }
}

// ---------------- kernel B: fused FC1..FC3, GT graphs per block -----------
#define FMA4(r, hv, wv)                                              \
    acc[r][0] = fmaf(hv, wv.x, acc[r][0]);                           \
    acc[r][1] = fmaf(hv, wv.y, acc[r][1]);                           \
    acc[r][2] = fmaf(hv, wv.z, acc[r][2]);                           \
    acc[r][3] = fmaf(hv, wv.w, acc[r][3]);

__global__ __launch_bounds__(NT)
void gcn_fc(const float* __restrict__ hbuf,
            const float* __restrict__ Wf1, const float* __restrict__ bf1,
            const float* __restrict__ Wf2, const float* __restrict__ bf2,
            const float* __restrict__ Wf3, const float* __restrict__ bf3,
            float* __restrict__ out, int B) {
    __shared__ float sH[GT * HSTR] __attribute__((aligned(16)));  // 59.4 KB, reused for z1/z2
    __shared__ float sWf3[840];
    __shared__ float sBf1[120], sBf2[84], sBf3[10];
    float* sZ1 = sH;            // [GT][120]
    float* sZ2 = sH + 4096;     // [GT][84]

    const int tid = threadIdx.x;
    const int g0  = blockIdx.x * GT;

    // ---- stage h tile + Wf3 + biases ----
    {
        const float4* hs = (const float4*)(hbuf + (size_t)g0 * HSTR);
        for (int i = tid; i < GT * HSTR / 4; i += NT) ((float4*)sH)[i] = hs[i];
        for (int i = tid; i < 840; i += NT) sWf3[i] = Wf3[i];
        if (tid < 120)                     sBf1[tid]       = bf1[tid];
        else if (tid >= 128 && tid < 212)  sBf2[tid - 128] = bf2[tid - 128];
        else if (tid >= 224 && tid < 234)  sBf3[tid - 224] = bf3[tid - 224];
    }
    __syncthreads();

    const int jq = tid & 31;          // column quad
    const int gq = tid >> 5;          // graph quad (0..7)
    float acc[4][4];

    // ---- FC1: z1 = elu(h @ Wf1 + bf1)   [GT,120] ----
    if (jq < 30) {
#pragma unroll
        for (int r = 0; r < 4; ++r)
#pragma unroll
            for (int c = 0; c < 4; ++c) acc[r][c] = 0.f;
        const float* hb = sH + gq * 4 * HSTR;
        const float* wp = Wf1 + jq * 4;
        int i = 0;
        for (; i < 460; i += 4) {
            float4 w0 = *(const float4*)(wp + (size_t)(i    ) * 120);
            float4 w1 = *(const float4*)(wp + (size_t)(i + 1) * 120);
            float4 w2 = *(const float4*)(wp + (size_t)(i + 2) * 120);
            float4 w3 = *(const float4*)(wp + (size_t)(i + 3) * 120);
#pragma unroll
            for (int r = 0; r < 4; ++r) {
                float4 h4 = *(const float4*)(hb + r * HSTR + i);
                FMA4(r, h4.x, w0); FMA4(r, h4.y, w1);
                FMA4(r, h4.z, w2); FMA4(r, h4.w, w3);
            }
        }
        for (; i < 462; ++i) {          // tail i = 460, 461
            float4 wv = make_float4(wp[(size_t)i*120], wp[(size_t)i*120+1],
                                    wp[(size_t)i*120+2], wp[(size_t)i*120+3]);
#pragma unroll
            for (int r = 0; r < 4; ++r) {
                float hv = hb[r * HSTR + i];
                FMA4(r, hv, wv);
            }
        }
    }
    __syncthreads();                    // all FC1 reads of sH done
    if (jq < 30) {
#pragma unroll
        for (int r = 0; r < 4; ++r)
#pragma unroll
            for (int c = 0; c < 4; ++c) {
                float v = acc[r][c] + sBf1[jq*4 + c];
                v = v > 0.f ? v : __expf(v) - 1.f;
                sZ1[(gq*4 + r) * 120 + jq*4 + c] = v;
            }
    }
    __syncthreads();

    // ---- FC2: z2 = elu(z1 @ Wf2 + bf2)   [GT,84] ----
    if (jq < 21) {
#pragma unroll
        for (int r = 0; r < 4; ++r)
#pragma unroll
            for (int c = 0; c < 4; ++c) acc[r][c] = 0.f;
        const float* zb = sZ1 + gq * 4 * 120;
        const float* wp = Wf2 + jq * 4;
        for (int i = 0; i < 120; i += 4) {
            float4 w0 = *(const float4*)(wp + (i    ) * 84);
            float4 w1 = *(const float4*)(wp + (i + 1) * 84);
            float4 w2 = *(const float4*)(wp + (i + 2) * 84);
            float4 w3 = *(const float4*)(wp + (i + 3) * 84);
#pragma unroll
            for (int r = 0; r < 4; ++r) {
                float4 z4 = *(const float4*)(zb + r * 120 + i);
                FMA4(r, z4.x, w0); FMA4(r, z4.y, w1);
                FMA4(r, z4.z, w2); FMA4(r, z4.w, w3);
            }
        }
#pragma unroll
        for (int r = 0; r < 4; ++r)
#pragma unroll
            for (int c = 0; c < 4; ++c) {
                float v = acc[r][c] + sBf2[jq*4 + c];
                v = v > 0.f ? v : __expf(v) - 1.f;
                sZ2[(gq*4 + r) * 84 + jq*4 + c] = v;
            }
    }
    __syncthreads();

    // ---- FC3 + store   [GT,10] ----
    for (int o = tid; o < GT * 10; o += NT) {
        int g = o / 10, j = o - g * 10;
        float acc3 = sBf3[j];
        const float* z = sZ2 + g * 84;
        for (int i = 0; i < 84; ++i) acc3 = fmaf(z[i], sWf3[i*10 + j], acc3);
        if (g0 + g < B) out[(size_t)(g0 + g) * 10 + j] = acc3;
    }
}

extern "C" void kernel_launch(void* const* d_in, const int* in_sizes, int n_in,
                              void* d_out, int out_size, void* d_ws, size_t ws_size,
                              hipStream_t stream) {
    const float* x   = (const float*)d_in[0];
    const int*   ei  = (const int*)d_in[1];
    const float* W1  = (const float*)d_in[2];
    const float* b1  = (const float*)d_in[3];
    const float* W2  = (const float*)d_in[4];
    const float* b2  = (const float*)d_in[5];
    const float* W3  = (const float*)d_in[6];
    const float* b3  = (const float*)d_in[7];
    const float* Wf1 = (const float*)d_in[8];
    const float* bf1 = (const float*)d_in[9];
    const float* Wf2 = (const float*)d_in[10];
    const float* bf2 = (const float*)d_in[11];
    const float* Wf3 = (const float*)d_in[12];
    const float* bf3 = (const float*)d_in[13];
    float* out = (float*)d_out;

    const int B = in_sizes[0] / (N_NODES * 12);

    // ws layout (bytes): offs@0 (1KB) | esrc@1024 (4.2KB) | enorm@5632 (8.3KB) | hbuf@16384
    int*   offs  = (int*)d_ws;
    short* esrc  = (short*)((char*)d_ws + 1024);
    float* enorm = (float*)((char*)d_ws + 5632);
    float* hbuf  = (float*)((char*)d_ws + 16384);

    gcn_setup<<<1, NT, 0, stream>>>(ei, offs, esrc, enorm);
    gcn_nodes<<<B, NT, 0, stream>>>(x, offs, esrc, enorm,
                                    W1, b1, W2, b2, W3, b3, hbuf, B);
    gcn_fc<<<(B + GT - 1) / GT, NT, 0, stream>>>(hbuf, Wf1, bf1, Wf2, bf2,
                                                 Wf3, bf3, out, B);
}